// Round 17
// baseline (77.860 us; speedup 1.0000x reference)
//
#include <hip/hip_runtime.h>
#include <hip/hip_bf16.h>

typedef __attribute__((ext_vector_type(8))) short short8;
typedef __attribute__((ext_vector_type(4))) float f32x4;

#define NTOK 1024
#define HDIM 1024
#define IDIM 1024
#define NEXP 8
#define NCOL 2048  // 2*I interleaved gate/up

// ---- workspace layout (bytes) ----
// counts padded: counts[e*32] (128B apart). q (tile queue) at +960.
#define WS_COUNTS   0
#define WS_Q        960
#define WS_LTOK     1024
#define WS_LW       (WS_LTOK + NEXP*NTOK*4)
#define WS_XBF      131072                                   // 1024x1024 bf16 = 2 MB
#define WS_ACT      (WS_XBF + NTOK*HDIM*2)                   // 2048x1024 bf16 = 4 MB
#define WS_W1B      (WS_ACT + 2*NTOK*IDIM*2)                 // 8x16x2048x64 bf16 = 32 MB
#define WS_W2B      (WS_W1B + (size_t)NEXP*NCOL*HDIM*2)      // 8x16x1024x64 bf16 = 16 MB

static __device__ __forceinline__ unsigned short f2bf(float x) {
    __hip_bfloat16 h = __float2bfloat16(x);   // RNE
    return __builtin_bit_cast(unsigned short, h);
}

#define GLDS16(g, l) __builtin_amdgcn_global_load_lds( \
    (const __attribute__((address_space(1))) void*)(g), \
    (__attribute__((address_space(3))) void*)(l), 16, 0, 0)

// In-register 4x4 transpose across lanes i=0..3 of a quad (R4-proven).
static __device__ __forceinline__ float4 xpose4(float4 v, int i) {
    float x = (i & 1) ? v.x : v.y;
    float y = (i & 1) ? v.z : v.w;
    x = __shfl_xor(x, 1); y = __shfl_xor(y, 1);
    if (i & 1) { v.x = x; v.z = y; } else { v.y = x; v.w = y; }
    float x2 = (i & 2) ? v.x : v.z;
    float y2 = (i & 2) ? v.y : v.w;
    x2 = __shfl_xor(x2, 2); y2 = __shfl_xor(y2, 2);
    if (i & 2) { v.x = x2; v.y = y2; } else { v.z = x2; v.w = y2; }
    return v;
}

// ---------------- prep: router (blocks 0..255), gup->w1b transpose 2-deep
// (blocks 256..2303, 2 adjacent 64x64 tiles each), out-zeroing (2304..2559).
// w1b[e][kb][col][kk], kb=k>>6, kk=k&63.
__global__ __launch_bounds__(256) void prep_kernel(
    const float* __restrict__ flat, const float* __restrict__ rw,
    const float* __restrict__ gup,
    float* __restrict__ scores, int* __restrict__ counts,
    int* __restrict__ ltok, float* __restrict__ lw,
    unsigned short* __restrict__ xbf, unsigned short* __restrict__ w1b,
    float* __restrict__ outz)
{
    __shared__ unsigned short tile[2][64][70];   // 17.9 KB
    const int b = blockIdx.x;
    const int t = threadIdx.x;

    if (b >= 2304) {
        // ---- zero the combine target (gemm2 atomics land on exact zeros) ----
        float4 z; z.x = 0.f; z.y = 0.f; z.z = 0.f; z.w = 0.f;
        float* d = outz + (size_t)(b - 2304) * 4096 + t * 4;
#pragma unroll
        for (int j = 0; j < 4; ++j)
            *(float4*)(d + j * 1024) = z;
        return;
    }

    if (b >= 256) {
        const int tid = b - 256;                   // 0..2047
        const int e = tid >> 8, rem = tid & 255, kb = rem >> 4, cbp = rem & 15;
        const int i4 = t & 3, g = t >> 2;
        const int rq = g >> 4, cq = (g & 15) * 4;
        // phase 1: ALL 8 loads (2 tiles) issued before any dependent op
        float4 vr[2][4];
#pragma unroll
        for (int u = 0; u < 2; ++u) {
            const float* s0 = gup + ((size_t)e * 1024 + kb * 64 + rq * 16 + i4) * NCOL
                             + (cbp * 2 + u) * 64 + cq;
#pragma unroll
            for (int it = 0; it < 4; ++it)
                vr[u][it] = *(const float4*)(s0 + (size_t)(it * 4) * NCOL);
        }
        const int c = cq + i4;
#pragma unroll
        for (int u = 0; u < 2; ++u)
#pragma unroll
            for (int it = 0; it < 4; ++it) {
                float4 v = xpose4(vr[u][it], i4);
                ushort4 o;
                o.x = f2bf(v.x); o.y = f2bf(v.y); o.z = f2bf(v.z); o.w = f2bf(v.w);
                *(ushort4*)&tile[u][c][rq * 16 + it * 4] = o;
            }
        __syncthreads();
        // phase 3: two adjacent 8 KB chunks -> 16 KB contiguous per block
        unsigned short* d0 = w1b + (((size_t)e * 16 + kb) * NCOL + cbp * 128) * 64;
#pragma unroll
        for (int u = 0; u < 2; ++u)
#pragma unroll
            for (int p = 0; p < 2; ++p) {
                int cc = p * 32 + (t >> 3), q = t & 7;
                short8 vv = *(const short8*)&tile[u][cc][q * 8];
                *(short8*)&d0[(size_t)(u * 64 + cc) * 64 + q * 8] = vv;
            }
        return;
    }

    // ---- router: 4 waves/block, one token per wave ----
    const int n = b * 4 + (t >> 6);
    const int l = t & 63;
    float acc[NEXP];
#pragma unroll
    for (int e = 0; e < NEXP; ++e) acc[e] = 0.f;
    const float* xrow = flat + (size_t)n * HDIM;
#pragma unroll
    for (int j = 0; j < 4; ++j) {
        int h = j * 256 + l * 4;
        float4 v = *(const float4*)&xrow[h];
        ushort4 xb;
        xb.x = f2bf(v.x); xb.y = f2bf(v.y); xb.z = f2bf(v.z); xb.w = f2bf(v.w);
        *(ushort4*)&xbf[(size_t)n * HDIM + h] = xb;
#pragma unroll
        for (int e = 0; e < NEXP; ++e) {
            float4 wv = *(const float4*)&rw[e * HDIM + h];
            acc[e] += v.x * wv.x + v.y * wv.y + v.z * wv.z + v.w * wv.w;
        }
    }
#pragma unroll
    for (int e = 0; e < NEXP; ++e) {
#pragma unroll
        for (int off = 32; off > 0; off >>= 1)
            acc[e] += __shfl_down(acc[e], off);
    }
    if (l == 0) {
        float m = acc[0];
#pragma unroll
        for (int e = 1; e < NEXP; ++e) m = fmaxf(m, acc[e]);
        float s = 0.f, p[NEXP];
#pragma unroll
        for (int e = 0; e < NEXP; ++e) { p[e] = __expf(acc[e] - m); s += p[e]; }
        float inv = 1.f / s;
#pragma unroll
        for (int e = 0; e < NEXP; ++e) { p[e] *= inv; scores[n * NEXP + e] = p[e]; }
        int i0 = 0;
#pragma unroll
        for (int e = 1; e < NEXP; ++e) if (p[e] > p[i0]) i0 = e;
        int i1 = (i0 == 0) ? 1 : 0;
#pragma unroll
        for (int e = 0; e < NEXP; ++e) if (e != i0 && p[e] > p[i1]) i1 = e;
        int pos0 = atomicAdd(&counts[i0 * 32], 1);
        ltok[i0 * NTOK + pos0] = n; lw[i0 * NTOK + pos0] = p[i0];
        int pos1 = atomicAdd(&counts[i1 * 32], 1);
        ltok[i1 * NTOK + pos1] = n; lw[i1 * NTOK + pos1] = p[i1];
    }
}

// ---------------- GEMM1 + spare-block dp->w2b transpose (4 tiles/batch) ----
// Working blocks (by*128 < cnt): BM=128 x BN=128, BK=64, 8 waves, wave 64x32.
// Spares pull 4 tiles per queue pop: each 256-thread half does 2 tiles with all
// 8 loads in flight (half 0 buffers overlay As, half 1 overlay Bs).
__global__ __launch_bounds__(512) void gemm1_kernel(
    const unsigned short* __restrict__ xbf, const unsigned short* __restrict__ w1b,
    const float* __restrict__ gbias,
    const int* __restrict__ counts,
    const int* __restrict__ ltok, unsigned short* __restrict__ act,
    const float* __restrict__ dp, unsigned short* __restrict__ w2b,
    int* __restrict__ tq)
{
    // bijective XCD swizzle over the 1024-block grid (1024 = 8 XCDs x 128)
    const int lin = blockIdx.x + (blockIdx.y << 4) + (blockIdx.z << 7);
    const int nlin = ((lin & 7) << 7) + (lin >> 3);
    const int bx = nlin & 15, by = (nlin >> 4) & 7, e = nlin >> 7;

    int cnt = 0, off = 0;
#pragma unroll
    for (int j2 = 0; j2 < NEXP; ++j2) {
        int c = counts[j2 * 32];
        if (j2 < e) off += c;
        if (j2 == e) cnt = c;
    }
    const int t = threadIdx.x;

    __shared__ unsigned short As[2][128][64];
    __shared__ unsigned short Bs[2][128][64];
    __shared__ int toks[128];
    __shared__ int tbase;

    if (by * 128 >= cnt) {
        // ---- spare block: dp -> w2b transpose worker, 2 tiles per half ----
        const int half = t >> 8, tt = t & 255;
        const int i4 = tt & 3, g = tt >> 2;
        const int rq = g >> 4, cq4 = (g & 15) * 4;
        unsigned short* tbuf = half ? &Bs[0][0][0] : &As[0][0][0];  // 2 x 4480 shorts
        for (;;) {
            if (t == 0) tbase = atomicAdd(tq, 4);
            __syncthreads();                       // tbase visible; prior reads done
            int base = tbase;
            if (base >= 2048) break;
            int myt0 = base + half * 2;
            // phase 1: all 8 loads (2 tiles) in flight
            float4 vr[2][4];
#pragma unroll
            for (int u = 0; u < 2; ++u) {
                int myt = myt0 + u;
                int te = myt >> 8, rem = myt & 255, kb = rem >> 4, cb = rem & 15;
                const float* s0 = dp + ((size_t)te * 1024 + kb * 64 + rq * 16 + i4) * HDIM
                                 + cb * 64 + cq4;
#pragma unroll
                for (int it = 0; it < 4; ++it)
                    vr[u][it] = *(const float4*)(s0 + (size_t)(it * 4) * HDIM);
            }
            const int c = cq4 + i4;
#pragma unroll
            for (int u = 0; u < 2; ++u)
#pragma unroll
                for (int it = 0; it < 4; ++it) {
                    float4 v = xpose4(vr[u][it], i4);
                    ushort4 o;
                    o.x = f2bf(v.x); o.y = f2bf(v.y); o.z = f2bf(v.z); o.w = f2bf(v.w);
                    *(ushort4*)&tbuf[u * 4480 + c * 70 + rq * 16 + it * 4] = o;
                }
            __syncthreads();
#pragma unroll
            for (int u = 0; u < 2; ++u) {
                int myt = myt0 + u;
                int te = myt >> 8, rem = myt & 255, kb = rem >> 4, cb = rem & 15;
                unsigned short* d0 = w2b + (((size_t)te * 16 + kb) * HDIM + cb * 64) * 64;
#pragma unroll
                for (int p = 0; p < 2; ++p) {
                    int cc = p * 32 + (tt >> 3), q = tt & 7;
                    short8 vv = *(const short8*)&tbuf[u * 4480 + cc * 70 + q * 8];
                    *(short8*)&d0[(size_t)cc * 64 + q * 8] = vv;
                }
            }
        }
        return;
    }

    const int l = t & 63, w = t >> 6;
    const int wm = w >> 2, wn = w & 3;
    if (t < 128) toks[t] = ltok[e * NTOK + min(by * 128 + t, cnt - 1)];
    __syncthreads();

    const int li = l & 7, lr = l >> 3;
    const int kswz = (li ^ lr) * 8;
    const unsigned short* asrc[2];
    const unsigned short* bsrc[2];
#pragma unroll
    for (int j = 0; j < 2; ++j) {
        int rr = (w * 2 + j) * 8 + lr;
        asrc[j] = xbf + (size_t)toks[rr] * HDIM + kswz;
        bsrc[j] = w1b + (size_t)e * 16 * NCOL * 64 + (size_t)(bx * 128 + rr) * 64 + kswz;
    }

    f32x4 acc[4][2];
#pragma unroll
    for (int m = 0; m < 4; ++m)
#pragma unroll
        for (int n = 0; n < 2; ++n) acc[m][n] = 0.f;

#pragma unroll
    for (int j = 0; j < 2; ++j) {
        GLDS16(asrc[j], &As[0][(w * 2 + j) * 8][0]);
        GLDS16(bsrc[j], &Bs[0][(w * 2 + j) * 8][0]);
    }

    const int lg = l >> 4, lo = l & 15;
    const int cq0 = ((0 + lg) ^ (lo & 7)) * 8;
    const int cq1 = ((4 + lg) ^ (lo & 7)) * 8;

    for (int ks = 0; ks < HDIM / 64; ++ks) {
        const int p = ks & 1;
        __builtin_amdgcn_s_barrier();     // closes compute(ks-1): back buffer free
        if (ks + 1 < HDIM / 64) {
            const int kadvA = (ks + 1) * 64;
            const size_t kadvB = (size_t)(ks + 1) * NCOL * 64;
#pragma unroll
            for (int j = 0; j < 2; ++j) {
                GLDS16(asrc[j] + kadvA, &As[p ^ 1][(w * 2 + j) * 8][0]);
                GLDS16(bsrc[j] + kadvB, &Bs[p ^ 1][(w * 2 + j) * 8][0]);
            }
            asm volatile("s_waitcnt vmcnt(4)" ::: "memory");
        } else {
            asm volatile("s_waitcnt vmcnt(0)" ::: "memory");
        }
        __builtin_amdgcn_sched_barrier(0);
        __builtin_amdgcn_s_barrier();     // all waves' ks-loads visible
        __builtin_amdgcn_s_setprio(1);
#pragma unroll
        for (int q = 0; q < 2; ++q) {
            const int cq = q ? cq1 : cq0;
            short8 a0 = *(const short8*)&As[p][wm * 64 +  0 + lo][cq];
            short8 a1 = *(const short8*)&As[p][wm * 64 + 16 + lo][cq];
            short8 a2 = *(const short8*)&As[p][wm * 64 + 32 + lo][cq];
            short8 a3 = *(const short8*)&As[p][wm * 64 + 48 + lo][cq];
            short8 b0 = *(const short8*)&Bs[p][wn * 32 +  0 + lo][cq];
            short8 b1 = *(const short8*)&Bs[p][wn * 32 + 16 + lo][cq];
#pragma unroll
            for (int m = 0; m < 4; ++m) {
                short8 am = (m == 0) ? a0 : (m == 1) ? a1 : (m == 2) ? a2 : a3;
                acc[m][0] = __builtin_amdgcn_mfma_f32_16x16x32_bf16(am, b0, acc[m][0], 0, 0, 0);
                acc[m][1] = __builtin_amdgcn_mfma_f32_16x16x32_bf16(am, b1, acc[m][1], 0, 0, 0);
            }
        }
        __builtin_amdgcn_s_setprio(0);
    }

    const int rj = lg * 4;
#pragma unroll
    for (int m = 0; m < 4; ++m) {
#pragma unroll
        for (int n = 0; n < 2; ++n) {
            int col = bx * 128 + wn * 32 + n * 16 + lo;
            float bias = gbias[e * NCOL + col];
#pragma unroll
            for (int j = 0; j < 4; ++j) {
                int slot = by * 128 + wm * 64 + m * 16 + rj + j;
                float val = acc[m][n][j] + bias;
                float other = __shfl_xor(val, 1);
                float g = (l & 1) ? other : val;
                float u = (l & 1) ? val : other;
                g = fminf(g, 7.f);
                u = fminf(fmaxf(u, -7.f), 7.f);
                float av = (u + 1.f) * g * (1.f / (1.f + __expf(-1.702f * g)));
                if (!(l & 1) && slot < cnt)
                    act[(size_t)(off + slot) * IDIM + (col >> 1)] = f2bf(av);
            }
        }
    }
}

// ---------------- GEMM2: out[tok][h] += (act @ W2b[e] + bias) * w  (atomic) ----
__global__ __launch_bounds__(512) void gemm2_kernel(
    const unsigned short* __restrict__ act, const unsigned short* __restrict__ w2b,
    const float* __restrict__ dbias,
    const int* __restrict__ counts,
    const int* __restrict__ ltok,
    const float* __restrict__ lw, float* __restrict__ outbuf)
{
    // bijective XCD swizzle (same 1024-block transform as gemm1)
    const int lin = blockIdx.x + (blockIdx.y << 4) + (blockIdx.z << 7);
    const int nlin = ((lin & 7) << 7) + (lin >> 3);
    const int bx = nlin & 15, by = (nlin >> 4) & 7, e = nlin >> 7;

    int cnt = 0, off = 0;
#pragma unroll
    for (int j2 = 0; j2 < NEXP; ++j2) {
        int c = counts[j2 * 32];
        if (j2 < e) off += c;
        if (j2 == e) cnt = c;
    }
    if (by * 128 >= cnt) return;
    const int t = threadIdx.x;
    const int l = t & 63, w = t >> 6;
    const int wm = w >> 1, wn = w & 1;

    __shared__ unsigned short As[2][128][64];
    __shared__ unsigned short Bs[2][64][64];
    __shared__ int toks[128];
    __shared__ float wts[128];
    if (t < 128) {
        int cl = min(by * 128 + t, cnt - 1);
        toks[t] = ltok[e * NTOK + cl];
        wts[t]  = lw[e * NTOK + cl];
    }
    __syncthreads();

    const int li = l & 7, lr = l >> 3;
    const int kswz = (li ^ lr) * 8;
    const unsigned short* asrc[2];
#pragma unroll
    for (int j = 0; j < 2; ++j) {
        int rr = (w * 2 + j) * 8 + lr;
        asrc[j] = act + (size_t)(off + min(by * 128 + rr, cnt - 1)) * IDIM + kswz;
    }
    const unsigned short* bsrc = w2b + (size_t)e * 16 * HDIM * 64
                               + (size_t)(bx * 64 + w * 8 + lr) * 64 + kswz;

    f32x4 acc[2][2];
#pragma unroll
    for (int m = 0; m < 2; ++m)
#pragma unroll
        for (int n = 0; n < 2; ++n) acc[m][n] = 0.f;

#pragma unroll
    for (int j = 0; j < 2; ++j)
        GLDS16(asrc[j], &As[0][(w * 2 + j) * 8][0]);
    GLDS16(bsrc, &Bs[0][w * 8][0]);

    const int lg = l >> 4, lo = l & 15;
    const int cq0 = ((0 + lg) ^ (lo & 7)) * 8;
    const int cq1 = ((4 + lg) ^ (lo & 7)) * 8;

    for (int ks = 0; ks < IDIM / 64; ++ks) {
        const int p = ks & 1;
        __builtin_amdgcn_s_barrier();
        if (ks + 1 < IDIM / 64) {
            const int kadvA = (ks + 1) * 64;
            const size_t kadvB = (size_t)(ks + 1) * HDIM * 64;
#pragma unroll
            for (int j = 0; j < 2; ++j)
                GLDS16(asrc[j] + kadvA, &As[p ^ 1][(w * 2 + j) * 8][0]);
            GLDS16(bsrc + kadvB, &Bs[p ^ 1][w * 8][0]);
            asm volatile("s_waitcnt vmcnt(3)" ::: "memory");
        } else {
            asm volatile("s_waitcnt vmcnt(0)" ::: "memory");
        }
        __builtin_amdgcn_sched_barrier(0);
        __builtin_amdgcn_s_barrier();
        __builtin_amdgcn_s_setprio(1);
#pragma unroll
        for (int q = 0; q < 2; ++q) {
            const int cq = q ? cq1 : cq0;
            short8 a0 = *(const short8*)&As[p][wm * 32 +  0 + lo][cq];
            short8 a1 = *(const short8*)&As[p][wm * 32 + 16 + lo][cq];
            short8 b0 = *(const short8*)&Bs[p][wn * 32 +  0 + lo][cq];
            short8 b1 = *(const short8*)&Bs[p][wn * 32 + 16 + lo][cq];
            acc[0][0] = __builtin_amdgcn_mfma_f32_16x16x32_bf16(a0, b0, acc[0][0], 0, 0, 0);
            acc[1][0] = __builtin_amdgcn_mfma_f32_16x16x32_bf16(a1, b0, acc[1][0], 0, 0, 0);
            acc[0][1] = __builtin_amdgcn_mfma_f32_16x16x32_bf16(a0, b1, acc[0][1], 0, 0, 0);
            acc[1][1] = __builtin_amdgcn_mfma_f32_16x16x32_bf16(a1, b1, acc[1][1], 0, 0, 0);
        }
        __builtin_amdgcn_s_setprio(0);
    }

    const int rj = lg * 4;
#pragma unroll
    for (int m = 0; m < 2; ++m) {
#pragma unroll
        for (int n = 0; n < 2; ++n) {
            int col = bx * 64 + wn * 32 + n * 16 + lo;
            float bias = dbias[e * HDIM + col];
#pragma unroll
            for (int j = 0; j < 4; ++j) {
                int sl = wm * 32 + m * 16 + rj + j;
                int slot = by * 128 + sl;
                if (slot < cnt) {
                    float val = (acc[m][n][j] + bias) * wts[sl];
                    atomicAdd(&outbuf[(size_t)toks[sl] * HDIM + col], val);
                }
            }
        }
    }
}

extern "C" void kernel_launch(void* const* d_in, const int* in_sizes, int n_in,
                              void* d_out, int out_size, void* d_ws, size_t ws_size,
                              hipStream_t stream) {
    const float* flat  = (const float*)d_in[0];
    const float* rw    = (const float*)d_in[1];
    const float* gup   = (const float*)d_in[2];
    const float* gbias = (const float*)d_in[3];
    const float* dp    = (const float*)d_in[4];
    const float* dbias = (const float*)d_in[5];
    float* out    = (float*)d_out;
    float* scores = out + (size_t)NTOK * HDIM;

    char* ws = (char*)d_ws;
    int*   counts  = (int*)(ws + WS_COUNTS);
    int*   tq      = (int*)(ws + WS_Q);
    int*   ltok    = (int*)(ws + WS_LTOK);
    float* lw      = (float*)(ws + WS_LW);
    unsigned short* xbf = (unsigned short*)(ws + WS_XBF);
    unsigned short* act = (unsigned short*)(ws + WS_ACT);
    unsigned short* w1b = (unsigned short*)(ws + WS_W1B);
    unsigned short* w2b = (unsigned short*)(ws + WS_W2B);

    hipMemsetAsync(ws, 0, 1024, stream);                          // counts + tq
    prep_kernel<<<2560, 256, 0, stream>>>(flat, rw, gup, scores, counts,
                                          ltok, lw, xbf, w1b, out);
    gemm1_kernel<<<dim3(16, 8, NEXP), 512, 0, stream>>>(xbf, w1b, gbias, counts,
                                                        ltok, act, dp, w2b, tq);
    gemm2_kernel<<<dim3(16, 8, NEXP), 512, 0, stream>>>(act, w2b, dbias, counts,
                                                        ltok, lw, out);
}

// Round 18
// 77.054 us; speedup vs baseline: 1.0105x; 1.0105x over previous
//
#include <hip/hip_runtime.h>
#include <hip/hip_bf16.h>

typedef __attribute__((ext_vector_type(8))) short short8;
typedef __attribute__((ext_vector_type(4))) float f32x4;

#define NTOK 1024
#define HDIM 1024
#define IDIM 1024
#define NEXP 8
#define NCOL 2048  // 2*I interleaved gate/up

// ---- workspace layout (bytes) ----
// counts padded: counts[e*32] (128B apart). q (tile queue) at +960.
#define WS_COUNTS   0
#define WS_Q        960
#define WS_LTOK     1024
#define WS_LW       (WS_LTOK + NEXP*NTOK*4)
#define WS_XBF      131072                                   // 1024x1024 bf16 = 2 MB
#define WS_ACT      (WS_XBF + NTOK*HDIM*2)                   // 2048x1024 bf16 = 4 MB
#define WS_W1B      (WS_ACT + 2*NTOK*IDIM*2)                 // 8x16x2048x64 bf16 = 32 MB
#define WS_W2B      (WS_W1B + (size_t)NEXP*NCOL*HDIM*2)      // 8x16x1024x64 bf16 = 16 MB

static __device__ __forceinline__ unsigned short f2bf(float x) {
    __hip_bfloat16 h = __float2bfloat16(x);   // RNE
    return __builtin_bit_cast(unsigned short, h);
}

#define GLDS16(g, l) __builtin_amdgcn_global_load_lds( \
    (const __attribute__((address_space(1))) void*)(g), \
    (__attribute__((address_space(3))) void*)(l), 16, 0, 0)

// In-register 4x4 transpose across lanes i=0..3 of a quad (R4-proven).
static __device__ __forceinline__ float4 xpose4(float4 v, int i) {
    float x = (i & 1) ? v.x : v.y;
    float y = (i & 1) ? v.z : v.w;
    x = __shfl_xor(x, 1); y = __shfl_xor(y, 1);
    if (i & 1) { v.x = x; v.z = y; } else { v.y = x; v.w = y; }
    float x2 = (i & 2) ? v.x : v.z;
    float y2 = (i & 2) ? v.y : v.w;
    x2 = __shfl_xor(x2, 2); y2 = __shfl_xor(y2, 2);
    if (i & 2) { v.x = x2; v.y = y2; } else { v.z = x2; v.w = y2; }
    return v;
}

// ---------------- prep: router (blocks 0..255), gup->w1b transpose
// (blocks 256..4351), out-zeroing (blocks 4352..4607).
// w1b[e][kb][col][kk], kb=k>>6, kk=k&63.
__global__ __launch_bounds__(256) void prep_kernel(
    const float* __restrict__ flat, const float* __restrict__ rw,
    const float* __restrict__ gup,
    float* __restrict__ scores, int* __restrict__ counts,
    int* __restrict__ ltok, float* __restrict__ lw,
    unsigned short* __restrict__ xbf, unsigned short* __restrict__ w1b,
    float* __restrict__ outz)
{
    __shared__ unsigned short tile[64][70];
    const int b = blockIdx.x;
    const int t = threadIdx.x;

    if (b >= 4352) {
        // ---- zero the combine target (gemm2 atomics land on exact zeros) ----
        float4 z; z.x = 0.f; z.y = 0.f; z.z = 0.f; z.w = 0.f;
        float* d = outz + (size_t)(b - 4352) * 4096 + t * 4;
#pragma unroll
        for (int j = 0; j < 4; ++j)
            *(float4*)(d + j * 1024) = z;
        return;
    }

    if (b >= 256) {
        const int tid = b - 256;                   // 0..4095
        const int e = tid >> 9, rem = tid & 511, kb = rem >> 5, cb = rem & 31;
        const int i4 = t & 3, g = t >> 2;
        const int rq = g >> 4, cq = (g & 15) * 4;
        const float* s0 = gup + ((size_t)e * 1024 + kb * 64 + rq * 16 + i4) * NCOL
                         + cb * 64 + cq;
        float4 vr[4];
#pragma unroll
        for (int it = 0; it < 4; ++it)
            vr[it] = *(const float4*)(s0 + (size_t)(it * 4) * NCOL);
        const int c = cq + i4;
#pragma unroll
        for (int it = 0; it < 4; ++it) {
            float4 v = xpose4(vr[it], i4);
            ushort4 o;
            o.x = f2bf(v.x); o.y = f2bf(v.y); o.z = f2bf(v.z); o.w = f2bf(v.w);
            *(ushort4*)&tile[c][rq * 16 + it * 4] = o;
        }
        __syncthreads();
        unsigned short* d0 = w1b + (((size_t)e * 16 + kb) * NCOL + cb * 64) * 64;
#pragma unroll
        for (int p = 0; p < 2; ++p) {
            int cc = p * 32 + (t >> 3), q = t & 7;
            short8 vv = *(const short8*)&tile[cc][q * 8];
            *(short8*)&d0[(size_t)cc * 64 + q * 8] = vv;
        }
        return;
    }

    // ---- router: 4 waves/block, one token per wave ----
    const int n = b * 4 + (t >> 6);
    const int l = t & 63;
    float acc[NEXP];
#pragma unroll
    for (int e = 0; e < NEXP; ++e) acc[e] = 0.f;
    const float* xrow = flat + (size_t)n * HDIM;
#pragma unroll
    for (int j = 0; j < 4; ++j) {
        int h = j * 256 + l * 4;
        float4 v = *(const float4*)&xrow[h];
        ushort4 xb;
        xb.x = f2bf(v.x); xb.y = f2bf(v.y); xb.z = f2bf(v.z); xb.w = f2bf(v.w);
        *(ushort4*)&xbf[(size_t)n * HDIM + h] = xb;
#pragma unroll
        for (int e = 0; e < NEXP; ++e) {
            float4 wv = *(const float4*)&rw[e * HDIM + h];
            acc[e] += v.x * wv.x + v.y * wv.y + v.z * wv.z + v.w * wv.w;
        }
    }
#pragma unroll
    for (int e = 0; e < NEXP; ++e) {
#pragma unroll
        for (int off = 32; off > 0; off >>= 1)
            acc[e] += __shfl_down(acc[e], off);
    }
    if (l == 0) {
        float m = acc[0];
#pragma unroll
        for (int e = 1; e < NEXP; ++e) m = fmaxf(m, acc[e]);
        float s = 0.f, p[NEXP];
#pragma unroll
        for (int e = 0; e < NEXP; ++e) { p[e] = __expf(acc[e] - m); s += p[e]; }
        float inv = 1.f / s;
#pragma unroll
        for (int e = 0; e < NEXP; ++e) { p[e] *= inv; scores[n * NEXP + e] = p[e]; }
        int i0 = 0;
#pragma unroll
        for (int e = 1; e < NEXP; ++e) if (p[e] > p[i0]) i0 = e;
        int i1 = (i0 == 0) ? 1 : 0;
#pragma unroll
        for (int e = 0; e < NEXP; ++e) if (e != i0 && p[e] > p[i1]) i1 = e;
        int pos0 = atomicAdd(&counts[i0 * 32], 1);
        ltok[i0 * NTOK + pos0] = n; lw[i0 * NTOK + pos0] = p[i0];
        int pos1 = atomicAdd(&counts[i1 * 32], 1);
        ltok[i1 * NTOK + pos1] = n; lw[i1 * NTOK + pos1] = p[i1];
    }
}

// ---------------- GEMM1 + spare-block dp->w2b transpose ----
// Working blocks (by*128 < cnt): BM=128 x BN=128, BK=64, 8 waves, wave 64x32.
// Early-exit blocks instead pull 64x64 dp-transpose tiles off an atomic queue.
// XCD relabel: works sharing (e,by) [the A-panel] land on one XCD's L2.
__global__ __launch_bounds__(512) void gemm1_kernel(
    const unsigned short* __restrict__ xbf, const unsigned short* __restrict__ w1b,
    const float* __restrict__ gbias,
    const int* __restrict__ counts,
    const int* __restrict__ ltok, unsigned short* __restrict__ act,
    const float* __restrict__ dp, unsigned short* __restrict__ w2b,
    int* __restrict__ tq)
{
    // bijective XCD swizzle over the 1024-block grid (1024 = 8 XCDs x 128)
    const int lin = blockIdx.x + (blockIdx.y << 4) + (blockIdx.z << 7);
    const int nlin = ((lin & 7) << 7) + (lin >> 3);
    const int bx = nlin & 15, by = (nlin >> 4) & 7, e = nlin >> 7;

    int cnt = 0, off = 0;
#pragma unroll
    for (int j2 = 0; j2 < NEXP; ++j2) {
        int c = counts[j2 * 32];
        if (j2 < e) off += c;
        if (j2 == e) cnt = c;
    }
    const int t = threadIdx.x;

    __shared__ unsigned short As[2][128][64];
    __shared__ unsigned short Bs[2][128][64];
    __shared__ int toks[128];
    __shared__ int tbase;

    if (by * 128 >= cnt) {
        // ---- spare block: dp -> w2b transpose worker (ttile overlays As) ----
        unsigned short (*ttile)[64][70] = (unsigned short (*)[64][70])(&As[0][0][0]);
        const int half = t >> 8, tt = t & 255;
        const int i4 = tt & 3, g = tt >> 2;
        const int rq = g >> 4, cq4 = (g & 15) * 4;
        for (;;) {
            if (t == 0) tbase = atomicAdd(tq, 2);
            __syncthreads();                       // tbase visible; prior reads done
            int base = tbase;
            if (base >= 2048) break;
            int myt = base + half;
            int te = myt >> 8, rem = myt & 255, kb = rem >> 4, cb = rem & 15;
            const float* s0 = dp + ((size_t)te * 1024 + kb * 64 + rq * 16 + i4) * HDIM
                             + cb * 64 + cq4;
            float4 vr[4];
#pragma unroll
            for (int it = 0; it < 4; ++it)
                vr[it] = *(const float4*)(s0 + (size_t)(it * 4) * HDIM);
            const int c = cq4 + i4;
#pragma unroll
            for (int it = 0; it < 4; ++it) {
                float4 v = xpose4(vr[it], i4);
                ushort4 o;
                o.x = f2bf(v.x); o.y = f2bf(v.y); o.z = f2bf(v.z); o.w = f2bf(v.w);
                *(ushort4*)&ttile[half][c][rq * 16 + it * 4] = o;
            }
            __syncthreads();
            unsigned short* d0 = w2b + (((size_t)te * 16 + kb) * HDIM + cb * 64) * 64;
#pragma unroll
            for (int p = 0; p < 2; ++p) {
                int cc = p * 32 + (tt >> 3), q = tt & 7;
                short8 vv = *(const short8*)&ttile[half][cc][q * 8];
                *(short8*)&d0[(size_t)cc * 64 + q * 8] = vv;
            }
        }
        return;
    }

    const int l = t & 63, w = t >> 6;
    const int wm = w >> 2, wn = w & 3;
    if (t < 128) toks[t] = ltok[e * NTOK + min(by * 128 + t, cnt - 1)];
    __syncthreads();

    const int li = l & 7, lr = l >> 3;
    const int kswz = (li ^ lr) * 8;
    const unsigned short* asrc[2];
    const unsigned short* bsrc[2];
#pragma unroll
    for (int j = 0; j < 2; ++j) {
        int rr = (w * 2 + j) * 8 + lr;
        asrc[j] = xbf + (size_t)toks[rr] * HDIM + kswz;
        bsrc[j] = w1b + (size_t)e * 16 * NCOL * 64 + (size_t)(bx * 128 + rr) * 64 + kswz;
    }

    f32x4 acc[4][2];
#pragma unroll
    for (int m = 0; m < 4; ++m)
#pragma unroll
        for (int n = 0; n < 2; ++n) acc[m][n] = 0.f;

#pragma unroll
    for (int j = 0; j < 2; ++j) {
        GLDS16(asrc[j], &As[0][(w * 2 + j) * 8][0]);
        GLDS16(bsrc[j], &Bs[0][(w * 2 + j) * 8][0]);
    }

    const int lg = l >> 4, lo = l & 15;
    const int cq0 = ((0 + lg) ^ (lo & 7)) * 8;
    const int cq1 = ((4 + lg) ^ (lo & 7)) * 8;

    for (int ks = 0; ks < HDIM / 64; ++ks) {
        const int p = ks & 1;
        __builtin_amdgcn_s_barrier();     // closes compute(ks-1): back buffer free
        if (ks + 1 < HDIM / 64) {
            const int kadvA = (ks + 1) * 64;
            const size_t kadvB = (size_t)(ks + 1) * NCOL * 64;
#pragma unroll
            for (int j = 0; j < 2; ++j) {
                GLDS16(asrc[j] + kadvA, &As[p ^ 1][(w * 2 + j) * 8][0]);
                GLDS16(bsrc[j] + kadvB, &Bs[p ^ 1][(w * 2 + j) * 8][0]);
            }
            asm volatile("s_waitcnt vmcnt(4)" ::: "memory");
        } else {
            asm volatile("s_waitcnt vmcnt(0)" ::: "memory");
        }
        __builtin_amdgcn_sched_barrier(0);
        __builtin_amdgcn_s_barrier();     // all waves' ks-loads visible
        __builtin_amdgcn_s_setprio(1);
#pragma unroll
        for (int q = 0; q < 2; ++q) {
            const int cq = q ? cq1 : cq0;
            short8 a0 = *(const short8*)&As[p][wm * 64 +  0 + lo][cq];
            short8 a1 = *(const short8*)&As[p][wm * 64 + 16 + lo][cq];
            short8 a2 = *(const short8*)&As[p][wm * 64 + 32 + lo][cq];
            short8 a3 = *(const short8*)&As[p][wm * 64 + 48 + lo][cq];
            short8 b0 = *(const short8*)&Bs[p][wn * 32 +  0 + lo][cq];
            short8 b1 = *(const short8*)&Bs[p][wn * 32 + 16 + lo][cq];
#pragma unroll
            for (int m = 0; m < 4; ++m) {
                short8 am = (m == 0) ? a0 : (m == 1) ? a1 : (m == 2) ? a2 : a3;
                acc[m][0] = __builtin_amdgcn_mfma_f32_16x16x32_bf16(am, b0, acc[m][0], 0, 0, 0);
                acc[m][1] = __builtin_amdgcn_mfma_f32_16x16x32_bf16(am, b1, acc[m][1], 0, 0, 0);
            }
        }
        __builtin_amdgcn_s_setprio(0);
    }

    const int rj = lg * 4;
#pragma unroll
    for (int m = 0; m < 4; ++m) {
#pragma unroll
        for (int n = 0; n < 2; ++n) {
            int col = bx * 128 + wn * 32 + n * 16 + lo;
            float bias = gbias[e * NCOL + col];
#pragma unroll
            for (int j = 0; j < 4; ++j) {
                int slot = by * 128 + wm * 64 + m * 16 + rj + j;
                float val = acc[m][n][j] + bias;
                float other = __shfl_xor(val, 1);
                float g = (l & 1) ? other : val;
                float u = (l & 1) ? val : other;
                g = fminf(g, 7.f);
                u = fminf(fmaxf(u, -7.f), 7.f);
                float av = (u + 1.f) * g * (1.f / (1.f + __expf(-1.702f * g)));
                if (!(l & 1) && slot < cnt)
                    act[(size_t)(off + slot) * IDIM + (col >> 1)] = f2bf(av);
            }
        }
    }
}

// ---------------- GEMM2: out[tok][h] += (act @ W2b[e] + bias) * w  (atomic) ----
__global__ __launch_bounds__(512) void gemm2_kernel(
    const unsigned short* __restrict__ act, const unsigned short* __restrict__ w2b,
    const float* __restrict__ dbias,
    const int* __restrict__ counts,
    const int* __restrict__ ltok,
    const float* __restrict__ lw, float* __restrict__ outbuf)
{
    // bijective XCD swizzle (same 1024-block transform as gemm1)
    const int lin = blockIdx.x + (blockIdx.y << 4) + (blockIdx.z << 7);
    const int nlin = ((lin & 7) << 7) + (lin >> 3);
    const int bx = nlin & 15, by = (nlin >> 4) & 7, e = nlin >> 7;

    int cnt = 0, off = 0;
#pragma unroll
    for (int j2 = 0; j2 < NEXP; ++j2) {
        int c = counts[j2 * 32];
        if (j2 < e) off += c;
        if (j2 == e) cnt = c;
    }
    if (by * 128 >= cnt) return;
    const int t = threadIdx.x;
    const int l = t & 63, w = t >> 6;
    const int wm = w >> 1, wn = w & 1;

    __shared__ unsigned short As[2][128][64];
    __shared__ unsigned short Bs[2][64][64];
    __shared__ int toks[128];
    __shared__ float wts[128];
    if (t < 128) {
        int cl = min(by * 128 + t, cnt - 1);
        toks[t] = ltok[e * NTOK + cl];
        wts[t]  = lw[e * NTOK + cl];
    }
    __syncthreads();

    const int li = l & 7, lr = l >> 3;
    const int kswz = (li ^ lr) * 8;
    const unsigned short* asrc[2];
#pragma unroll
    for (int j = 0; j < 2; ++j) {
        int rr = (w * 2 + j) * 8 + lr;
        asrc[j] = act + (size_t)(off + min(by * 128 + rr, cnt - 1)) * IDIM + kswz;
    }
    const unsigned short* bsrc = w2b + (size_t)e * 16 * HDIM * 64
                               + (size_t)(bx * 64 + w * 8 + lr) * 64 + kswz;

    f32x4 acc[2][2];
#pragma unroll
    for (int m = 0; m < 2; ++m)
#pragma unroll
        for (int n = 0; n < 2; ++n) acc[m][n] = 0.f;

#pragma unroll
    for (int j = 0; j < 2; ++j)
        GLDS16(asrc[j], &As[0][(w * 2 + j) * 8][0]);
    GLDS16(bsrc, &Bs[0][w * 8][0]);

    const int lg = l >> 4, lo = l & 15;
    const int cq0 = ((0 + lg) ^ (lo & 7)) * 8;
    const int cq1 = ((4 + lg) ^ (lo & 7)) * 8;

    for (int ks = 0; ks < IDIM / 64; ++ks) {
        const int p = ks & 1;
        __builtin_amdgcn_s_barrier();
        if (ks + 1 < IDIM / 64) {
            const int kadvA = (ks + 1) * 64;
            const size_t kadvB = (size_t)(ks + 1) * HDIM * 64;
#pragma unroll
            for (int j = 0; j < 2; ++j)
                GLDS16(asrc[j] + kadvA, &As[p ^ 1][(w * 2 + j) * 8][0]);
            GLDS16(bsrc + kadvB, &Bs[p ^ 1][w * 8][0]);
            asm volatile("s_waitcnt vmcnt(3)" ::: "memory");
        } else {
            asm volatile("s_waitcnt vmcnt(0)" ::: "memory");
        }
        __builtin_amdgcn_sched_barrier(0);
        __builtin_amdgcn_s_barrier();
        __builtin_amdgcn_s_setprio(1);
#pragma unroll
        for (int q = 0; q < 2; ++q) {
            const int cq = q ? cq1 : cq0;
            short8 a0 = *(const short8*)&As[p][wm * 32 +  0 + lo][cq];
            short8 a1 = *(const short8*)&As[p][wm * 32 + 16 + lo][cq];
            short8 b0 = *(const short8*)&Bs[p][wn * 32 +  0 + lo][cq];
            short8 b1 = *(const short8*)&Bs[p][wn * 32 + 16 + lo][cq];
            acc[0][0] = __builtin_amdgcn_mfma_f32_16x16x32_bf16(a0, b0, acc[0][0], 0, 0, 0);
            acc[1][0] = __builtin_amdgcn_mfma_f32_16x16x32_bf16(a1, b0, acc[1][0], 0, 0, 0);
            acc[0][1] = __builtin_amdgcn_mfma_f32_16x16x32_bf16(a0, b1, acc[0][1], 0, 0, 0);
            acc[1][1] = __builtin_amdgcn_mfma_f32_16x16x32_bf16(a1, b1, acc[1][1], 0, 0, 0);
        }
        __builtin_amdgcn_s_setprio(0);
    }

    const int rj = lg * 4;
#pragma unroll
    for (int m = 0; m < 2; ++m) {
#pragma unroll
        for (int n = 0; n < 2; ++n) {
            int col = bx * 64 + wn * 32 + n * 16 + lo;
            float bias = dbias[e * HDIM + col];
#pragma unroll
            for (int j = 0; j < 4; ++j) {
                int sl = wm * 32 + m * 16 + rj + j;
                int slot = by * 128 + sl;
                if (slot < cnt) {
                    float val = (acc[m][n][j] + bias) * wts[sl];
                    atomicAdd(&outbuf[(size_t)toks[sl] * HDIM + col], val);
                }
            }
        }
    }
}

extern "C" void kernel_launch(void* const* d_in, const int* in_sizes, int n_in,
                              void* d_out, int out_size, void* d_ws, size_t ws_size,
                              hipStream_t stream) {
    const float* flat  = (const float*)d_in[0];
    const float* rw    = (const float*)d_in[1];
    const float* gup   = (const float*)d_in[2];
    const float* gbias = (const float*)d_in[3];
    const float* dp    = (const float*)d_in[4];
    const float* dbias = (const float*)d_in[5];
    float* out    = (float*)d_out;
    float* scores = out + (size_t)NTOK * HDIM;

    char* ws = (char*)d_ws;
    int*   counts  = (int*)(ws + WS_COUNTS);
    int*   tq      = (int*)(ws + WS_Q);
    int*   ltok    = (int*)(ws + WS_LTOK);
    float* lw      = (float*)(ws + WS_LW);
    unsigned short* xbf = (unsigned short*)(ws + WS_XBF);
    unsigned short* act = (unsigned short*)(ws + WS_ACT);
    unsigned short* w1b = (unsigned short*)(ws + WS_W1B);
    unsigned short* w2b = (unsigned short*)(ws + WS_W2B);

    hipMemsetAsync(ws, 0, 1024, stream);                          // counts + tq
    prep_kernel<<<4608, 256, 0, stream>>>(flat, rw, gup, scores, counts,
                                          ltok, lw, xbf, w1b, out);
    gemm1_kernel<<<dim3(16, 8, NEXP), 512, 0, stream>>>(xbf, w1b, gbias, counts,
                                                        ltok, act, dp, w2b, tq);
    gemm2_kernel<<<dim3(16, 8, NEXP), 512, 0, stream>>>(act, w2b, dbias, counts,
                                                        ltok, lw, out);
}